// Round 10
// baseline (187.253 us; speedup 1.0000x reference)
//
#include <hip/hip_runtime.h>

// Problem constants
#define U_CNT 784   // H*W = 28*28 (both u and v extents)
#define DKH   128   // key/value head dim
#define DD    512   // input channel dim
#define NS    16    // support classes

typedef short bf16x8 __attribute__((ext_vector_type(8)));
typedef float f32x4  __attribute__((ext_vector_type(4)));

__device__ __forceinline__ unsigned short f2bf(float f) {
  unsigned u = __builtin_bit_cast(unsigned, f);
  u += 0x7fffu + ((u >> 16) & 1u);   // round-to-nearest-even
  return (unsigned short)(u >> 16);
}

// Fragment-major layouts (bf16); every MFMA fragment load = 64x16B contiguous:
//   x_f [m][pt(49)][c(64)][ul(16)][8] : input X transposed+bf16 (c = d/8)
//   q_f [b][ut(49)][c(16)][ul(16)][8] : scaled query keys (scale incl. log2e)
//   sk_f[v][c(16)][class(16)][8]

// ---------------------------------------------------------------- K0: cast W
__global__ void cast_w(const float* __restrict__ Wk, const float* __restrict__ Wv,
                       unsigned short* __restrict__ Wkv) {
  int base = (blockIdx.x * 256 + threadIdx.x) * 8;
#pragma unroll
  for (int i = 0; i < 8; ++i) {
    int e = base + i;
    int ko = e >> 9, d = e & 511;
    float v = (ko < 128) ? Wk[ko * 512 + d] : Wv[(ko - 128) * 512 + d];
    Wkv[e] = f2bf(v);
  }
}

// ------------------------------------------------- K0b: X -> bf16 frag-major
// Block = (d-slab of 32, image m). Reads FULL 3136B rows coalesced, converts
// to bf16, transposes via swizzled LDS, writes x_f in 1KB contiguous runs.
__global__ __launch_bounds__(256)
void xpose_kernel(const float* __restrict__ query, const float* __restrict__ support,
                  unsigned short* __restrict__ x_f) {
  __shared__ unsigned short lds[784 * 34];   // [p][swiz(d_local)]
  int s = blockIdx.x;   // 0..15 slab (32 d-rows)
  int m = blockIdx.y;   // 0..23
  const float* X = (m < 8) ? (query + (size_t)m * DD * U_CNT)
                           : (support + (size_t)(m - 8) * DD * U_CNT);
  int tid = threadIdx.x;
  // stage: 32 rows x 196 float4, fully coalesced global reads
  for (int i = 0; i < 25; ++i) {
    int idx = i * 256 + tid;
    if (idx < 6272) {
      int row = idx / 196, c4 = idx - row * 196;
      float4 v = *(const float4*)(X + (size_t)(s * 32 + row) * U_CNT + c4 * 4);
      float vv[4] = {v.x, v.y, v.z, v.w};
#pragma unroll
      for (int cc = 0; cc < 4; ++cc) {
        int p = c4 * 4 + cc;
        int sw = row ^ ((p & 15) << 1);    // even-XOR swizzle keeps d-pairs
        lds[p * 34 + sw] = f2bf(vv[cc]);
      }
    }
  }
  __syncthreads();
  // emit: 12544 ushort2 = 49 exact iters; dest contiguous 256B per wave-instr
  unsigned short* xb = x_f + (size_t)m * 401408;
  for (int i = 0; i < 49; ++i) {
    int idx = i * 256 + tid;
    int pt = idx >> 8, rem = idx & 255;
    int cl = rem >> 6, q2 = rem & 63, ul = q2 >> 2, jj = (q2 & 3) * 2;
    int p = pt * 16 + ul;
    int dl = cl * 8 + jj;
    int sw = dl ^ ((p & 15) << 1);         // even -> ushort2 stays paired
    ushort2 o = *(const ushort2*)(&lds[p * 34 + sw]);
    *(ushort2*)(xb + (size_t)pt * 8192 + (s * 4 + cl) * 128 + ul * 8 + jj) = o;
  }
}

// ------------------------------------------------------------- K1: projection
// Score-style streaming GEMM: grid (49 pt, 24 m), 4 waves x 4 row-groups.
// B-frags from x_f (1KB contiguous, double-buffered), A-frags Wkv from L2.
__global__ __launch_bounds__(256, 4)
void proj_kernel(const unsigned short* __restrict__ x_f,
                 const unsigned short* __restrict__ Wkv,
                 unsigned short* __restrict__ q_f, unsigned short* __restrict__ sk_f,
                 float* __restrict__ sv_t, float* __restrict__ S1p, float* __restrict__ S2p) {
  int pt = blockIdx.x;        // 0..48
  int m  = blockIdx.y;        // 0..23
  int tid = threadIdx.x;
  int wave = tid >> 6, l = tid & 63;
  int col = l & 15, rowg = l >> 4;

  const unsigned short* xb =
      x_f + (size_t)m * 401408 + (size_t)pt * 8192 + rowg * 128 + col * 8;
  f32x4 acc[4];
  f32x4 zero = {0.f, 0.f, 0.f, 0.f};
#pragma unroll
  for (int rr = 0; rr < 4; ++rr) acc[rr] = zero;

  bf16x8 Bcur = *(const bf16x8*)(xb);
  for (int ds = 0; ds < 16; ++ds) {
    int nds = (ds + 1 < 16) ? ds + 1 : ds;
    bf16x8 Bnxt = *(const bf16x8*)(xb + nds * 512);
    bf16x8 Af[4];
#pragma unroll
    for (int rr = 0; rr < 4; ++rr)
      Af[rr] = *(const bf16x8*)(Wkv + (size_t)((wave * 4 + rr) * 16 + col) * DD +
                                ds * 32 + rowg * 8);
#pragma unroll
    for (int rr = 0; rr < 4; ++rr)
      acc[rr] = __builtin_amdgcn_mfma_f32_16x16x32_bf16(Af[rr], Bcur, acc[rr], 0, 0, 0);
    Bcur = Bnxt;
  }

  // ------------------------------- epilogue ---------------------------------
  if (m < 8) {
    if (wave < 2) {
      // rows 0..127 -> q_f fragment-major; scale = 1/sqrt(128) * log2(e)
#pragma unroll
      for (int rr = 0; rr < 4; ++rr) {
        int r = wave * 4 + rr;          // 0..7
        const float sc = 0.12751744f;
        ushort4 o;
        o.x = f2bf(acc[rr][0] * sc); o.y = f2bf(acc[rr][1] * sc);
        o.z = f2bf(acc[rr][2] * sc); o.w = f2bf(acc[rr][3] * sc);
        size_t off = (size_t)m * 100352 + (size_t)pt * 2048 +
                     (size_t)(2 * r + (rowg >> 1)) * 128 + col * 8 + (rowg & 1) * 4;
        *(ushort4*)(q_f + off) = o;
      }
    } else {
      float s1 = 0.f;
#pragma unroll
      for (int rr = 0; rr < 4; ++rr) {
        int r = wave * 4 + rr;          // 8..15
#pragma unroll
        for (int j = 0; j < 4; ++j) {
          float x = acc[rr][j];
          s1 += x * x;
          x += __shfl_xor(x, 1, 64); x += __shfl_xor(x, 2, 64);
          x += __shfl_xor(x, 4, 64); x += __shfl_xor(x, 8, 64);
          if (col == 0)
            S2p[((size_t)pt * 8 + m) * DKH + (r - 8) * 16 + rowg * 4 + j] = x;
        }
      }
#pragma unroll
      for (int o = 32; o >= 1; o >>= 1) s1 += __shfl_xor(s1, o, 64);
      if (l == 0) S1p[((wave - 2) * 49 + pt) * 8 + m] = s1;
    }
  } else {
    int img = m - 8;
    if (wave < 2) {
#pragma unroll
      for (int rr = 0; rr < 4; ++rr) {
        int r = wave * 4 + rr;          // 0..7
        ushort4 o;
        o.x = f2bf(acc[rr][0]); o.y = f2bf(acc[rr][1]);
        o.z = f2bf(acc[rr][2]); o.w = f2bf(acc[rr][3]);
        size_t off = (size_t)(pt * 16 + col) * 2048 +
                     (size_t)(2 * r + (rowg >> 1)) * 128 + img * 8 + (rowg & 1) * 4;
        *(ushort4*)(sk_f + off) = o;
      }
    } else {
#pragma unroll
      for (int rr = 0; rr < 4; ++rr) {
        int r = wave * 4 + rr;
        int kb = (r - 8) * 16 + rowg * 4;
        float4 o = make_float4(acc[rr][0], acc[rr][1], acc[rr][2], acc[rr][3]);
        *(float4*)(sv_t + (size_t)(img * U_CNT + pt * 16 + col) * DKH + kb) = o;
      }
    }
  }
}

// -------------------------------------------- K3: scores + softmax_n + sum_u
// 1568 blocks (49 vb x 4 uc x 8 b); fragment loads 1KB contiguous; B dbuf'd.
// exp2 (v_exp_f32) with log2e folded into q_f scale.
__global__ __launch_bounds__(256, 4)
void score_kernel(const unsigned short* __restrict__ q_f,
                  const unsigned short* __restrict__ sk_f,
                  float* __restrict__ w_part) {
  int bx = blockIdx.x;            // 1568 = 49 vb * 4 uc * 8 b
  int vb = bx % 49;
  int uc = (bx / 49) & 3;
  int b  = bx / 196;
  int wv = threadIdx.x >> 6;
  int l  = threadIdx.x & 63;
  int col = l & 15, rowg = l >> 4;
  int vbase = vb * 16 + wv * 4;

  bf16x8 A[4][4];
#pragma unroll
  for (int v = 0; v < 4; ++v) {
    const unsigned short* ap = sk_f + (size_t)(vbase + v) * 2048 + rowg * 128 + col * 8;
#pragma unroll
    for (int s = 0; s < 4; ++s) A[v][s] = *(const bf16x8*)(ap + s * 512);
  }

  float wl[4][4];
#pragma unroll
  for (int v = 0; v < 4; ++v)
#pragma unroll
    for (int j = 0; j < 4; ++j) wl[v][j] = 0.f;

  int ut0 = (uc == 0) ? 0 : uc * 12 + 1;       // u-tile split 13/12/12/12
  int cnt = (uc == 0) ? 13 : 12;
  const unsigned short* qb = q_f + (size_t)b * 100352 + rowg * 128 + col * 8;
  f32x4 zero = {0.f, 0.f, 0.f, 0.f};

  const unsigned short* qp0 = qb + (size_t)ut0 * 2048;
  bf16x8 B0 = *(const bf16x8*)(qp0);
  bf16x8 B1 = *(const bf16x8*)(qp0 + 512);
  bf16x8 B2 = *(const bf16x8*)(qp0 + 1024);
  bf16x8 B3 = *(const bf16x8*)(qp0 + 1536);

  for (int it = 0; it < cnt; ++it) {
    int nit = (it + 1 < cnt) ? it + 1 : it;
    const unsigned short* qp = qb + (size_t)(ut0 + nit) * 2048;
    bf16x8 N0 = *(const bf16x8*)(qp);
    bf16x8 N1 = *(const bf16x8*)(qp + 512);
    bf16x8 N2 = *(const bf16x8*)(qp + 1024);
    bf16x8 N3 = *(const bf16x8*)(qp + 1536);

    f32x4 acc[4];
#pragma unroll
    for (int v = 0; v < 4; ++v) acc[v] = zero;
#pragma unroll
    for (int v = 0; v < 4; ++v)
      acc[v] = __builtin_amdgcn_mfma_f32_16x16x32_bf16(A[v][0], B0, acc[v], 0, 0, 0);
#pragma unroll
    for (int v = 0; v < 4; ++v)
      acc[v] = __builtin_amdgcn_mfma_f32_16x16x32_bf16(A[v][1], B1, acc[v], 0, 0, 0);
#pragma unroll
    for (int v = 0; v < 4; ++v)
      acc[v] = __builtin_amdgcn_mfma_f32_16x16x32_bf16(A[v][2], B2, acc[v], 0, 0, 0);
#pragma unroll
    for (int v = 0; v < 4; ++v)
      acc[v] = __builtin_amdgcn_mfma_f32_16x16x32_bf16(A[v][3], B3, acc[v], 0, 0, 0);
#pragma unroll
    for (int v = 0; v < 4; ++v) {
      float e0 = __builtin_amdgcn_exp2f(acc[v][0]);
      float e1 = __builtin_amdgcn_exp2f(acc[v][1]);
      float e2 = __builtin_amdgcn_exp2f(acc[v][2]);
      float e3 = __builtin_amdgcn_exp2f(acc[v][3]);
      float ps = (e0 + e1) + (e2 + e3);
      ps += __shfl_xor(ps, 16, 64);
      ps += __shfl_xor(ps, 32, 64);
      float r = __builtin_amdgcn_rcpf(ps);
      wl[v][0] += e0 * r; wl[v][1] += e1 * r;
      wl[v][2] += e2 * r; wl[v][3] += e3 * r;
    }
    B0 = N0; B1 = N1; B2 = N2; B3 = N3;
  }
#pragma unroll
  for (int v = 0; v < 4; ++v)
#pragma unroll
    for (int j = 0; j < 4; ++j) {
      float x = wl[v][j];
      x += __shfl_xor(x, 1, 64); x += __shfl_xor(x, 2, 64);
      x += __shfl_xor(x, 4, 64); x += __shfl_xor(x, 8, 64);
      wl[v][j] = x;
    }
  __shared__ float wst[4][4][16];   // [wave][v_local][class]
#pragma unroll
  for (int v = 0; v < 4; ++v)
    if (col == v) {
#pragma unroll
      for (int j = 0; j < 4; ++j) wst[wv][v][rowg * 4 + j] = wl[v][j];
    }
  __syncthreads();
  int t = threadIdx.x;
  int vl = t >> 4, c = t & 15;
  w_part[(((size_t)uc * 8 + b) * U_CNT + vb * 16 + vl) * NS + c] =
      wst[vl >> 2][vl & 3][c];
}

// --------------------------- K4: a = sum_n w*sv -> per-block partials (T1p,T2p)
__global__ __launch_bounds__(256)
void align_kernel(const float* __restrict__ w_part, const float* __restrict__ sv_t,
                  float* __restrict__ T1p, float* __restrict__ T2p) {
  int vt2 = blockIdx.x;   // 0..391
  int t = threadIdx.x;
  __shared__ float w_sh[2][8][16];   // [v_local][b][class]
  {
    int vl = t >> 7, b = (t >> 4) & 7, n = t & 15;
    float s = 0.f;
#pragma unroll
    for (int uc = 0; uc < 4; ++uc)
      s += w_part[(((size_t)uc * 8 + b) * U_CNT + vt2 * 2 + vl) * NS + n];
    w_sh[vl][b][n] = s;
  }
  __syncthreads();
  int k = t & 127, vl = t >> 7;
  int v = vt2 * 2 + vl;
  float a[8];
#pragma unroll
  for (int b = 0; b < 8; ++b) a[b] = 0.f;
#pragma unroll
  for (int n = 0; n < NS; ++n) {
    float s = sv_t[((size_t)n * U_CNT + v) * DKH + k];
#pragma unroll
    for (int b = 0; b < 8; ++b) a[b] += w_sh[vl][b][n] * s;
  }
  __shared__ float red[8][128];
  if (vl == 1) {
#pragma unroll
    for (int b = 0; b < 8; ++b) red[b][k] = a[b];
  }
  __syncthreads();
  if (vl == 0) {
#pragma unroll
    for (int b = 0; b < 8; ++b)
      T2p[((size_t)vt2 * 8 + b) * DKH + k] = a[b] + red[b][k];
  }
  __shared__ float sw1[4][8];
#pragma unroll
  for (int b = 0; b < 8; ++b) {
    float x = a[b] * a[b];
#pragma unroll
    for (int o = 32; o >= 1; o >>= 1) x += __shfl_xor(x, o, 64);
    if ((t & 63) == 0) sw1[t >> 6][b] = x;
  }
  __syncthreads();
  if (t < 8) T1p[vt2 * 8 + t] = sw1[0][t] + sw1[1][t] + sw1[2][t] + sw1[3][t];
}

// ------------------------------- K5a: parallel partial reduction (40 blocks)
__global__ __launch_bounds__(256)
void reduce_partials(const float* __restrict__ S1p, const float* __restrict__ T1p,
                     const float* __restrict__ S2p, const float* __restrict__ T2p,
                     float* __restrict__ S2, float* __restrict__ T2,
                     float* __restrict__ ST1) {
  __shared__ float smem[264];
  int bx = blockIdx.x, t = threadIdx.x;
  if (bx < 32) {
    int b = bx >> 2, kq = bx & 3;
    int kl = t & 31, g = t >> 5;           // 8 groups x 32 k-lanes
    int k = kq * 32 + kl;
    float s = 0.f;
    for (int w = g; w < 392; w += 8)
      s += T2p[((size_t)w * 8 + b) * DKH + k];
    smem[g * 32 + kl] = s;
    __syncthreads();
    if (t < 32) {
      float v = 0.f;
#pragma unroll
      for (int g2 = 0; g2 < 8; ++g2) v += smem[g2 * 32 + t];
      T2[b * DKH + kq * 32 + t] = v;
    }
  } else {
    int b = bx - 32;
    int k = t & 127, h = t >> 7;
    float s = 0.f;
    for (int w = h; w < 49; w += 2)
      s += S2p[((size_t)w * 8 + b) * DKH + k];
    if (h == 1) smem[k] = s;
    __syncthreads();
    if (h == 0) S2[b * DKH + k] = s + smem[k];
    float c = 0.f;
    for (int i = t; i < 98; i += 256)  c += S1p[i * 8 + b];
    for (int i = t; i < 392; i += 256) c += T1p[i * 8 + b];
#pragma unroll
    for (int o = 32; o >= 1; o >>= 1) c += __shfl_xor(c, o, 64);
    if ((t & 63) == 0) smem[256 + (t >> 6)] = c;
    __syncthreads();
    if (t == 0) ST1[b] = smem[256] + smem[257] + smem[258] + smem[259];
  }
}

// ----------------------------------------------------------------- K5b: final
__global__ void final_kernel(const float* __restrict__ S2, const float* __restrict__ T2,
                             const float* __restrict__ ST1, float* __restrict__ out) {
  int b = blockIdx.x, t = threadIdx.x;  // 128 threads
  float p = S2[b * DKH + t] * T2[b * DKH + t];
#pragma unroll
  for (int o = 32; o >= 1; o >>= 1) p += __shfl_xor(p, o, 64);
  __shared__ float s2[2];
  if ((t & 63) == 0) s2[t >> 6] = p;
  __syncthreads();
  if (t == 0)
    out[b] = (784.0f * ST1[b] - 2.0f * (s2[0] + s2[1])) * (1.0f / (784.0f * 784.0f));
}

// ----------------------------------------------------------------- launcher
extern "C" void kernel_launch(void* const* d_in, const int* in_sizes, int n_in,
                              void* d_out, int out_size, void* d_ws, size_t ws_size,
                              hipStream_t stream) {
  const float* query   = (const float*)d_in[0];
  const float* support = (const float*)d_in[1];
  const float* Wk      = (const float*)d_in[2];
  const float* Wv      = (const float*)d_in[3];
  float* out = (float*)d_out;
  char* ws = (char*)d_ws;

  // workspace layout (256B-aligned)
  unsigned short* Wkv  = (unsigned short*)(ws + 0);          //  256KB
  unsigned short* q_f  = (unsigned short*)(ws + 262144);     //  bf16 [8][49][16][16][8]
  unsigned short* sk_f = (unsigned short*)(ws + 1867776);    //  bf16 [784][16][16][8]
  float*          sv_t = (float*)(ws + 5079040);             //  f32  [16][784][128]
  float*          w_part = (float*)(ws + 11501568);          //  f32  [4][8][784][16]
  unsigned short* x_f  = (unsigned short*)(ws + 13107200);   //  bf16 [24][49][64][16][8] 19.3MB
  float*          S1p  = (float*)(ws + 32374784);            //  [98][8]
  float*          T1p  = (float*)(ws + 32378880);            //  [392][8]
  float*          S2p  = (float*)(ws + 32395264);            //  [49][8][128]
  float*          T2p  = (float*)(ws + 32595968);            //  [392][8][128]
  float*          S2   = (float*)(ws + 34201600);            //  [8][128]
  float*          T2   = (float*)(ws + 34205696);            //  [8][128]
  float*          ST1  = (float*)(ws + 34209792);            //  [8]
  if (ws_size < (size_t)34210000) return;

  cast_w<<<64, 256, 0, stream>>>(Wk, Wv, Wkv);
  xpose_kernel<<<dim3(16, 24), 256, 0, stream>>>(query, support, x_f);
  proj_kernel<<<dim3(49, 24), 256, 0, stream>>>(x_f, Wkv, q_f, sk_f, sv_t, S1p, S2p);
  score_kernel<<<1568, 256, 0, stream>>>(q_f, sk_f, w_part);
  align_kernel<<<392, 256, 0, stream>>>(w_part, sv_t, T1p, T2p);
  reduce_partials<<<40, 256, 0, stream>>>(S1p, T1p, S2p, T2p, S2, T2, ST1);
  final_kernel<<<8, 128, 0, stream>>>(S2, T2, ST1, out);
}

// Round 11
// 162.367 us; speedup vs baseline: 1.1533x; 1.1533x over previous
//
#include <hip/hip_runtime.h>

// Problem constants
#define U_CNT 784   // H*W = 28*28 (both u and v extents)
#define DKH   128   // key/value head dim
#define DD    512   // input channel dim
#define NQ    8
#define NS    16    // support classes

typedef short bf16x8 __attribute__((ext_vector_type(8)));
typedef float f32x4  __attribute__((ext_vector_type(4)));

__device__ __forceinline__ unsigned short f2bf(float f) {
  unsigned u = __builtin_bit_cast(unsigned, f);
  u += 0x7fffu + ((u >> 16) & 1u);   // round-to-nearest-even
  return (unsigned short)(u >> 16);
}

// Fragment-major layouts (bf16); every MFMA fragment load = 64x16B contiguous:
//   Wkv_f[frag=r*16+ds][lane(64)][8] : weights (r = out-row-group, ds = k-chunk)
//   x_f [m][pt(49)][c(64)][ul(16)][8] : input X transposed+bf16 (c = d/8)
//   q_f [b][ut(49)][c(16)][ul(16)][8] : scaled query keys (scale incl. log2e)
//   sk_f[v][c(16)][class(16)][8]

// ------------------------------------------- K0: cast W -> fragment-major bf16
__global__ void cast_w(const float* __restrict__ Wk, const float* __restrict__ Wv,
                       unsigned short* __restrict__ Wkv_f) {
  int i = blockIdx.x * 256 + threadIdx.x;   // 16384 lanes total
  int f = i >> 6, l = i & 63;
  int r = f >> 4, ds = f & 15;
  int col = l & 15, rowg = l >> 4;
  int ko = r * 16 + col;
  int d0 = ds * 32 + rowg * 8;
  const float* src = (ko < 128) ? (Wk + (size_t)ko * 512 + d0)
                                : (Wv + (size_t)(ko - 128) * 512 + d0);
  unsigned short o[8];
#pragma unroll
  for (int j = 0; j < 8; ++j) o[j] = f2bf(src[j]);
  ushort4 lo = {o[0], o[1], o[2], o[3]}, hi = {o[4], o[5], o[6], o[7]};
  *(ushort4*)(Wkv_f + (size_t)i * 8) = lo;
  *(ushort4*)(Wkv_f + (size_t)i * 8 + 4) = hi;
}

// ------------------------------------------------- K0b: X -> bf16 frag-major
// Block = (d-slab of 32, image m). Reads FULL 3136B rows coalesced, converts
// to bf16, transposes via swizzled LDS, writes x_f in 1KB contiguous runs.
__global__ __launch_bounds__(256)
void xpose_kernel(const float* __restrict__ query, const float* __restrict__ support,
                  unsigned short* __restrict__ x_f) {
  __shared__ unsigned short lds[784 * 34];   // [p][swiz(d_local)]
  int s = blockIdx.x;   // 0..15 slab (32 d-rows)
  int m = blockIdx.y;   // 0..23
  const float* X = (m < 8) ? (query + (size_t)m * DD * U_CNT)
                           : (support + (size_t)(m - 8) * DD * U_CNT);
  int tid = threadIdx.x;
  // stage: 32 rows x 196 float4, fully coalesced global reads
  for (int i = 0; i < 25; ++i) {
    int idx = i * 256 + tid;
    if (idx < 6272) {
      int row = idx / 196, c4 = idx - row * 196;
      float4 v = *(const float4*)(X + (size_t)(s * 32 + row) * U_CNT + c4 * 4);
      float vv[4] = {v.x, v.y, v.z, v.w};
#pragma unroll
      for (int cc = 0; cc < 4; ++cc) {
        int p = c4 * 4 + cc;
        int sw = row ^ ((p & 15) << 1);    // even-XOR swizzle keeps d-pairs
        lds[p * 34 + sw] = f2bf(vv[cc]);
      }
    }
  }
  __syncthreads();
  // emit: 12544 ushort2 = 49 exact iters; dest contiguous 256B per wave-instr
  unsigned short* xb = x_f + (size_t)m * 401408;
  for (int i = 0; i < 49; ++i) {
    int idx = i * 256 + tid;
    int pt = idx >> 8, rem = idx & 255;
    int cl = rem >> 6, q2 = rem & 63, ul = q2 >> 2, jj = (q2 & 3) * 2;
    int p = pt * 16 + ul;
    int dl = cl * 8 + jj;
    int sw = dl ^ ((p & 15) << 1);         // even -> ushort2 stays paired
    ushort2 o = *(const ushort2*)(&lds[p * 34 + sw]);
    *(ushort2*)(xb + (size_t)pt * 8192 + (s * 4 + cl) * 128 + ul * 8 + jj) = o;
  }
}

// ------------------------------------------------------------- K1: projection
// Pure streaming GEMM: grid (49 pt, 24 m), 4 waves x 4 row-groups. EVERY load
// (A from Wkv_f, B from x_f) is a 64-lane contiguous 1KB transaction.
__global__ __launch_bounds__(256, 4)
void proj_kernel(const unsigned short* __restrict__ x_f,
                 const unsigned short* __restrict__ Wkv_f,
                 unsigned short* __restrict__ q_f, unsigned short* __restrict__ sk_f,
                 float* __restrict__ sv_t, float* __restrict__ S1p, float* __restrict__ S2p) {
  int pt = blockIdx.x;        // 0..48
  int m  = blockIdx.y;        // 0..23
  int tid = threadIdx.x;
  int wave = tid >> 6, l = tid & 63;
  int col = l & 15, rowg = l >> 4;

  const unsigned short* xb =
      x_f + (size_t)m * 401408 + (size_t)pt * 8192 + l * 8;
  const unsigned short* wb = Wkv_f + (size_t)(wave * 4) * 16 * 512 + l * 8;
  f32x4 acc[4];
  f32x4 zero = {0.f, 0.f, 0.f, 0.f};
#pragma unroll
  for (int rr = 0; rr < 4; ++rr) acc[rr] = zero;

  bf16x8 Bcur = *(const bf16x8*)(xb);
  for (int ds = 0; ds < 16; ++ds) {
    int nds = (ds + 1 < 16) ? ds + 1 : ds;
    bf16x8 Bnxt = *(const bf16x8*)(xb + nds * 512);
    bf16x8 Af[4];
#pragma unroll
    for (int rr = 0; rr < 4; ++rr)
      Af[rr] = *(const bf16x8*)(wb + (size_t)(rr * 16 + ds) * 512);
#pragma unroll
    for (int rr = 0; rr < 4; ++rr)
      acc[rr] = __builtin_amdgcn_mfma_f32_16x16x32_bf16(Af[rr], Bcur, acc[rr], 0, 0, 0);
    Bcur = Bnxt;
  }

  // ------------------------------- epilogue ---------------------------------
  if (m < 8) {
    if (wave < 2) {
      // rows 0..127 -> q_f fragment-major; scale = 1/sqrt(128) * log2(e)
#pragma unroll
      for (int rr = 0; rr < 4; ++rr) {
        int r = wave * 4 + rr;          // 0..7
        const float sc = 0.12751744f;
        ushort4 o;
        o.x = f2bf(acc[rr][0] * sc); o.y = f2bf(acc[rr][1] * sc);
        o.z = f2bf(acc[rr][2] * sc); o.w = f2bf(acc[rr][3] * sc);
        size_t off = (size_t)m * 100352 + (size_t)pt * 2048 +
                     (size_t)(2 * r + (rowg >> 1)) * 128 + col * 8 + (rowg & 1) * 4;
        *(ushort4*)(q_f + off) = o;
      }
    } else {
      float s1 = 0.f;
#pragma unroll
      for (int rr = 0; rr < 4; ++rr) {
        int r = wave * 4 + rr;          // 8..15
#pragma unroll
        for (int j = 0; j < 4; ++j) {
          float x = acc[rr][j];
          s1 += x * x;
          x += __shfl_xor(x, 1, 64); x += __shfl_xor(x, 2, 64);
          x += __shfl_xor(x, 4, 64); x += __shfl_xor(x, 8, 64);
          if (col == 0)
            S2p[((size_t)pt * 8 + m) * DKH + (r - 8) * 16 + rowg * 4 + j] = x;
        }
      }
#pragma unroll
      for (int o = 32; o >= 1; o >>= 1) s1 += __shfl_xor(s1, o, 64);
      if (l == 0) S1p[((wave - 2) * 49 + pt) * 8 + m] = s1;
    }
  } else {
    int img = m - 8;
    if (wave < 2) {
#pragma unroll
      for (int rr = 0; rr < 4; ++rr) {
        int r = wave * 4 + rr;          // 0..7
        ushort4 o;
        o.x = f2bf(acc[rr][0]); o.y = f2bf(acc[rr][1]);
        o.z = f2bf(acc[rr][2]); o.w = f2bf(acc[rr][3]);
        size_t off = (size_t)(pt * 16 + col) * 2048 +
                     (size_t)(2 * r + (rowg >> 1)) * 128 + img * 8 + (rowg & 1) * 4;
        *(ushort4*)(sk_f + off) = o;
      }
    } else {
#pragma unroll
      for (int rr = 0; rr < 4; ++rr) {
        int r = wave * 4 + rr;
        int kb = (r - 8) * 16 + rowg * 4;
        float4 o = make_float4(acc[rr][0], acc[rr][1], acc[rr][2], acc[rr][3]);
        *(float4*)(sv_t + (size_t)(img * U_CNT + pt * 16 + col) * DKH + kb) = o;
      }
    }
  }
}

// -------------------------------------------- K3: scores + softmax_n + sum_u
// 1568 blocks (49 vb x 4 uc x 8 b); fragment loads 1KB contiguous; B dbuf'd.
// exp2 (v_exp_f32) with log2e folded into q_f scale.
__global__ __launch_bounds__(256, 4)
void score_kernel(const unsigned short* __restrict__ q_f,
                  const unsigned short* __restrict__ sk_f,
                  float* __restrict__ w_part) {
  int bx = blockIdx.x;            // 1568 = 49 vb * 4 uc * 8 b
  int vb = bx % 49;
  int uc = (bx / 49) & 3;
  int b  = bx / 196;
  int wv = threadIdx.x >> 6;
  int l  = threadIdx.x & 63;
  int col = l & 15, rowg = l >> 4;
  int vbase = vb * 16 + wv * 4;

  bf16x8 A[4][4];
#pragma unroll
  for (int v = 0; v < 4; ++v) {
    const unsigned short* ap = sk_f + (size_t)(vbase + v) * 2048 + rowg * 128 + col * 8;
#pragma unroll
    for (int s = 0; s < 4; ++s) A[v][s] = *(const bf16x8*)(ap + s * 512);
  }

  float wl[4][4];
#pragma unroll
  for (int v = 0; v < 4; ++v)
#pragma unroll
    for (int j = 0; j < 4; ++j) wl[v][j] = 0.f;

  int ut0 = (uc == 0) ? 0 : uc * 12 + 1;       // u-tile split 13/12/12/12
  int cnt = (uc == 0) ? 13 : 12;
  const unsigned short* qb = q_f + (size_t)b * 100352 + rowg * 128 + col * 8;
  f32x4 zero = {0.f, 0.f, 0.f, 0.f};

  const unsigned short* qp0 = qb + (size_t)ut0 * 2048;
  bf16x8 B0 = *(const bf16x8*)(qp0);
  bf16x8 B1 = *(const bf16x8*)(qp0 + 512);
  bf16x8 B2 = *(const bf16x8*)(qp0 + 1024);
  bf16x8 B3 = *(const bf16x8*)(qp0 + 1536);

  for (int it = 0; it < cnt; ++it) {
    int nit = (it + 1 < cnt) ? it + 1 : it;
    const unsigned short* qp = qb + (size_t)(ut0 + nit) * 2048;
    bf16x8 N0 = *(const bf16x8*)(qp);
    bf16x8 N1 = *(const bf16x8*)(qp + 512);
    bf16x8 N2 = *(const bf16x8*)(qp + 1024);
    bf16x8 N3 = *(const bf16x8*)(qp + 1536);

    f32x4 acc[4];
#pragma unroll
    for (int v = 0; v < 4; ++v) acc[v] = zero;
#pragma unroll
    for (int v = 0; v < 4; ++v)
      acc[v] = __builtin_amdgcn_mfma_f32_16x16x32_bf16(A[v][0], B0, acc[v], 0, 0, 0);
#pragma unroll
    for (int v = 0; v < 4; ++v)
      acc[v] = __builtin_amdgcn_mfma_f32_16x16x32_bf16(A[v][1], B1, acc[v], 0, 0, 0);
#pragma unroll
    for (int v = 0; v < 4; ++v)
      acc[v] = __builtin_amdgcn_mfma_f32_16x16x32_bf16(A[v][2], B2, acc[v], 0, 0, 0);
#pragma unroll
    for (int v = 0; v < 4; ++v)
      acc[v] = __builtin_amdgcn_mfma_f32_16x16x32_bf16(A[v][3], B3, acc[v], 0, 0, 0);
#pragma unroll
    for (int v = 0; v < 4; ++v) {
      float e0 = __builtin_amdgcn_exp2f(acc[v][0]);
      float e1 = __builtin_amdgcn_exp2f(acc[v][1]);
      float e2 = __builtin_amdgcn_exp2f(acc[v][2]);
      float e3 = __builtin_amdgcn_exp2f(acc[v][3]);
      float ps = (e0 + e1) + (e2 + e3);
      ps += __shfl_xor(ps, 16, 64);
      ps += __shfl_xor(ps, 32, 64);
      float r = __builtin_amdgcn_rcpf(ps);
      wl[v][0] += e0 * r; wl[v][1] += e1 * r;
      wl[v][2] += e2 * r; wl[v][3] += e3 * r;
    }
    B0 = N0; B1 = N1; B2 = N2; B3 = N3;
  }
#pragma unroll
  for (int v = 0; v < 4; ++v)
#pragma unroll
    for (int j = 0; j < 4; ++j) {
      float x = wl[v][j];
      x += __shfl_xor(x, 1, 64); x += __shfl_xor(x, 2, 64);
      x += __shfl_xor(x, 4, 64); x += __shfl_xor(x, 8, 64);
      wl[v][j] = x;
    }
  __shared__ float wst[4][4][16];   // [wave][v_local][class]
#pragma unroll
  for (int v = 0; v < 4; ++v)
    if (col == v) {
#pragma unroll
      for (int j = 0; j < 4; ++j) wst[wv][v][rowg * 4 + j] = wl[v][j];
    }
  __syncthreads();
  int t = threadIdx.x;
  int vl = t >> 4, c = t & 15;
  w_part[(((size_t)uc * 8 + b) * U_CNT + vb * 16 + vl) * NS + c] =
      wst[vl >> 2][vl & 3][c];
}

// --------------------------- K4: a = sum_n w*sv -> per-block partials (T1p,T2p)
__global__ __launch_bounds__(256)
void align_kernel(const float* __restrict__ w_part, const float* __restrict__ sv_t,
                  float* __restrict__ T1p, float* __restrict__ T2p) {
  int vt2 = blockIdx.x;   // 0..391
  int t = threadIdx.x;
  __shared__ float w_sh[2][8][16];   // [v_local][b][class]
  {
    int vl = t >> 7, b = (t >> 4) & 7, n = t & 15;
    float s = 0.f;
#pragma unroll
    for (int uc = 0; uc < 4; ++uc)
      s += w_part[(((size_t)uc * 8 + b) * U_CNT + vt2 * 2 + vl) * NS + n];
    w_sh[vl][b][n] = s;
  }
  __syncthreads();
  int k = t & 127, vl = t >> 7;
  int v = vt2 * 2 + vl;
  float a[8];
#pragma unroll
  for (int b = 0; b < 8; ++b) a[b] = 0.f;
#pragma unroll
  for (int n = 0; n < NS; ++n) {
    float s = sv_t[((size_t)n * U_CNT + v) * DKH + k];
#pragma unroll
    for (int b = 0; b < 8; ++b) a[b] += w_sh[vl][b][n] * s;
  }
  __shared__ float red[8][128];
  if (vl == 1) {
#pragma unroll
    for (int b = 0; b < 8; ++b) red[b][k] = a[b];
  }
  __syncthreads();
  if (vl == 0) {
#pragma unroll
    for (int b = 0; b < 8; ++b)
      T2p[((size_t)vt2 * 8 + b) * DKH + k] = a[b] + red[b][k];
  }
  __shared__ float sw1[4][8];
#pragma unroll
  for (int b = 0; b < 8; ++b) {
    float x = a[b] * a[b];
#pragma unroll
    for (int o = 32; o >= 1; o >>= 1) x += __shfl_xor(x, o, 64);
    if ((t & 63) == 0) sw1[t >> 6][b] = x;
  }
  __syncthreads();
  if (t < 8) T1p[vt2 * 8 + t] = sw1[0][t] + sw1[1][t] + sw1[2][t] + sw1[3][t];
}

// ------------------------------- K5a: parallel partial reduction (40 blocks)
__global__ __launch_bounds__(256)
void reduce_partials(const float* __restrict__ S1p, const float* __restrict__ T1p,
                     const float* __restrict__ S2p, const float* __restrict__ T2p,
                     float* __restrict__ S2, float* __restrict__ T2,
                     float* __restrict__ ST1) {
  __shared__ float smem[264];
  int bx = blockIdx.x, t = threadIdx.x;
  if (bx < 32) {
    int b = bx >> 2, kq = bx & 3;
    int kl = t & 31, g = t >> 5;           // 8 groups x 32 k-lanes
    int k = kq * 32 + kl;
    float s = 0.f;
    for (int w = g; w < 392; w += 8)
      s += T2p[((size_t)w * 8 + b) * DKH + k];
    smem[g * 32 + kl] = s;
    __syncthreads();
    if (t < 32) {
      float v = 0.f;
#pragma unroll
      for (int g2 = 0; g2 < 8; ++g2) v += smem[g2 * 32 + t];
      T2[b * DKH + kq * 32 + t] = v;
    }
  } else {
    int b = bx - 32;
    int k = t & 127, h = t >> 7;
    float s = 0.f;
    for (int w = h; w < 49; w += 2)
      s += S2p[((size_t)w * 8 + b) * DKH + k];
    if (h == 1) smem[k] = s;
    __syncthreads();
    if (h == 0) S2[b * DKH + k] = s + smem[k];
    float c = 0.f;
    for (int i = t; i < 98; i += 256)  c += S1p[i * 8 + b];
    for (int i = t; i < 392; i += 256) c += T1p[i * 8 + b];
#pragma unroll
    for (int o = 32; o >= 1; o >>= 1) c += __shfl_xor(c, o, 64);
    if ((t & 63) == 0) smem[256 + (t >> 6)] = c;
    __syncthreads();
    if (t == 0) ST1[b] = smem[256] + smem[257] + smem[258] + smem[259];
  }
}

// ----------------------------------------------------------------- K5b: final
__global__ void final_kernel(const float* __restrict__ S2, const float* __restrict__ T2,
                             const float* __restrict__ ST1, float* __restrict__ out) {
  int b = blockIdx.x, t = threadIdx.x;  // 128 threads
  float p = S2[b * DKH + t] * T2[b * DKH + t];
#pragma unroll
  for (int o = 32; o >= 1; o >>= 1) p += __shfl_xor(p, o, 64);
  __shared__ float s2[2];
  if ((t & 63) == 0) s2[t >> 6] = p;
  __syncthreads();
  if (t == 0)
    out[b] = (784.0f * ST1[b] - 2.0f * (s2[0] + s2[1])) * (1.0f / (784.0f * 784.0f));
}

// ----------------------------------------------------------------- launcher
extern "C" void kernel_launch(void* const* d_in, const int* in_sizes, int n_in,
                              void* d_out, int out_size, void* d_ws, size_t ws_size,
                              hipStream_t stream) {
  const float* query   = (const float*)d_in[0];
  const float* support = (const float*)d_in[1];
  const float* Wk      = (const float*)d_in[2];
  const float* Wv      = (const float*)d_in[3];
  float* out = (float*)d_out;
  char* ws = (char*)d_ws;

  // workspace layout (256B-aligned)
  unsigned short* Wkv_f = (unsigned short*)(ws + 0);         //  256KB frag-major
  unsigned short* q_f  = (unsigned short*)(ws + 262144);     //  bf16 [8][49][16][16][8]
  unsigned short* sk_f = (unsigned short*)(ws + 1867776);    //  bf16 [784][16][16][8]
  float*          sv_t = (float*)(ws + 5079040);             //  f32  [16][784][128]
  float*          w_part = (float*)(ws + 11501568);          //  f32  [4][8][784][16]
  unsigned short* x_f  = (unsigned short*)(ws + 13107200);   //  bf16 [24][49][64][16][8] 19.3MB
  float*          S1p  = (float*)(ws + 32374784);            //  [98][8]
  float*          T1p  = (float*)(ws + 32378880);            //  [392][8]
  float*          S2p  = (float*)(ws + 32395264);            //  [49][8][128]
  float*          T2p  = (float*)(ws + 32595968);            //  [392][8][128]
  float*          S2   = (float*)(ws + 34201600);            //  [8][128]
  float*          T2   = (float*)(ws + 34205696);            //  [8][128]
  float*          ST1  = (float*)(ws + 34209792);            //  [8]
  if (ws_size < (size_t)34210000) return;

  cast_w<<<64, 256, 0, stream>>>(Wk, Wv, Wkv_f);
  xpose_kernel<<<dim3(16, 24), 256, 0, stream>>>(query, support, x_f);
  proj_kernel<<<dim3(49, 24), 256, 0, stream>>>(x_f, Wkv_f, q_f, sk_f, sv_t, S1p, S2p);
  score_kernel<<<1568, 256, 0, stream>>>(q_f, sk_f, w_part);
  align_kernel<<<392, 256, 0, stream>>>(w_part, sv_t, T1p, T2p);
  reduce_partials<<<40, 256, 0, stream>>>(S1p, T1p, S2p, T2p, S2, T2, ST1);
  final_kernel<<<8, 128, 0, stream>>>(S2, T2, ST1, out);
}